// Round 6
// baseline (1209.740 us; speedup 1.0000x reference)
//
#include <hip/hip_runtime.h>
#include <hip/hip_bf16.h>

// ---------------------------------------------------------------------------
// B=2,S=2048,D=1024; M=4096 rows. N_QK=N_V=4096, N_KNOW=8192.
// bf16x4 split GEMM (K-extended to 4096) on 32x32x16 MFMA -> fp32-class
// scores; gates select exact tie-correct top-k via bitwise binary search.
// Stage order: KNOW first (scores -> [gQ|gK] region as aligned scratch,
// gate writes misaligned gKn with scalar stores), then QK (in-place), then V.
// LDS seg XOR swizzle (seg' = seg ^ (row&7)) keeps fragment ds_read_b128 at
// the 8-cyc throughput floor (round-5: conflicts 1e8 -> 0).
// ---------------------------------------------------------------------------

#define M_ROWS 4096
#define DIM    1024
#define KX     4096   // 4*DIM:  A'=[H|H|L|L],  B'=[H|L|H|L]
#define N_QK   4096
#define N_KNOW 8192

typedef unsigned short ushortT;
typedef __attribute__((ext_vector_type(8)))  short short8;   // 8 bf16 (4 VGPR)
typedef __attribute__((ext_vector_type(4)))  float f32x4;
typedef __attribute__((ext_vector_type(16))) float f32x16;

// ---------------------------------------------------------------------------
// tau kernel
// ---------------------------------------------------------------------------
__global__ __launch_bounds__(256) void tau_kernel(
    const float* __restrict__ x, const float* __restrict__ w_attn,
    const float* __restrict__ b_attn, const float* __restrict__ w_know,
    const float* __restrict__ b_know, float* __restrict__ tau4, int D)
{
    __shared__ float s_f[4][4];
    const int row = blockIdx.x;
    const int tid = threadIdx.x;
    const float* xr = x + (size_t)row * D;
    float p0 = 0.f, p1 = 0.f, p2 = 0.f, p3 = 0.f;
    for (int d = tid; d < D; d += 256) {
        float xv = xr[d];
        p0 += xv * w_attn[d * 3 + 0];
        p1 += xv * w_attn[d * 3 + 1];
        p2 += xv * w_attn[d * 3 + 2];
        p3 += xv * w_know[d];
    }
#pragma unroll
    for (int o = 32; o > 0; o >>= 1) {
        p0 += __shfl_down(p0, o, 64);
        p1 += __shfl_down(p1, o, 64);
        p2 += __shfl_down(p2, o, 64);
        p3 += __shfl_down(p3, o, 64);
    }
    const int lane = tid & 63, wv = tid >> 6;
    if (lane == 0) { s_f[wv][0] = p0; s_f[wv][1] = p1; s_f[wv][2] = p2; s_f[wv][3] = p3; }
    __syncthreads();
    if (tid < 4) {
        float v = s_f[0][tid] + s_f[1][tid] + s_f[2][tid] + s_f[3][tid];
        v += (tid < 3) ? b_attn[tid] : b_know[0];
        tau4[(size_t)row * 4 + tid] = v;
    }
}

// ---------------------------------------------------------------------------
// convert: rows x 1024 fp32 -> rows x 4096 bf16.
//   MODE_A: [H | H | L | L]     MODE_B: [H | L | H | L]
// ---------------------------------------------------------------------------
template <bool IS_A>
__global__ __launch_bounds__(256) void convert_ext(
    const float* __restrict__ src, ushortT* __restrict__ dst, int nElem4)
{
    int g = blockIdx.x * 256 + threadIdx.x;
    if (g >= nElem4) return;
    int row = g >> 8;            // 256 float4 groups per row
    int k4  = (g & 255) << 2;    // 0..1020
    const float4 v = *(const float4*)(src + (size_t)row * DIM + k4);
    float vv[4] = {v.x, v.y, v.z, v.w};
    ushortT hi[4], lo[4];
#pragma unroll
    for (int i = 0; i < 4; i++) {
        __hip_bfloat16 hb = __float2bfloat16(vv[i]);
        float r = vv[i] - __bfloat162float(hb);
        __hip_bfloat16 lb = __float2bfloat16(r);
        hi[i] = *(ushortT*)&hb; lo[i] = *(ushortT*)&lb;
    }
    ushort4 H = make_ushort4(hi[0], hi[1], hi[2], hi[3]);
    ushort4 L = make_ushort4(lo[0], lo[1], lo[2], lo[3]);
    ushortT* drow = dst + (size_t)row * KX;
    if (IS_A) {
        *(ushort4*)(drow + k4)            = H;
        *(ushort4*)(drow + DIM + k4)      = H;
        *(ushort4*)(drow + 2 * DIM + k4)  = L;
        *(ushort4*)(drow + 3 * DIM + k4)  = L;
    } else {
        *(ushort4*)(drow + k4)            = H;
        *(ushort4*)(drow + DIM + k4)      = L;
        *(ushort4*)(drow + 2 * DIM + k4)  = H;
        *(ushort4*)(drow + 3 * DIM + k4)  = L;
    }
}

// ---------------------------------------------------------------------------
// bf16 NT GEMM: 128x128 tile, BK=64, 256 thr = 2x2 waves, 64x64/wave as
// 2x2 of 32x32x16 MFMA (higher FLOP/issue than 16x16x32; m119: 2495 TF).
// A/B frag: [m|n = lane&31][k = (lane>>5)*8 + j]  (2xK-family mapping)
// C/D frag: col=lane&31, row=(reg&3)+8*(reg>>2)+4*(lane>>5)  [m74/m101]
// LDS [128 rows][8 segs x 16B], slot (r, sp) holds global seg sp^(r&7).
// ---------------------------------------------------------------------------
__global__ __launch_bounds__(256) void gemm_bt_bf16x4(
    const ushortT* __restrict__ A, const ushortT* __restrict__ B,
    float* __restrict__ C, long long ldc)
{
    __shared__ ushortT As[128 * 64];
    __shared__ ushortT Bs[128 * 64];
    const int tid = threadIdx.x;
    const int wave = tid >> 6, lane = tid & 63;
    const int l32 = lane & 31, h = lane >> 5;
    const int rx7 = l32 & 7;
    const int wm = (wave >> 1) * 64, wn = (wave & 1) * 64;
    const long long m0 = (long long)blockIdx.y * 128;
    const long long n0 = (long long)blockIdx.x * 128;

    f32x16 acc[2][2] = {};

    const ushortT* gA[4];
    const ushortT* gB[4];
    ushortT* lA[4];
    ushortT* lB[4];
#pragma unroll
    for (int it = 0; it < 4; ++it) {
        int f = it * 256 + tid;          // 0..1023 flat 16B slot
        int r = f >> 3, sp = f & 7;      // row 0..127, lds seg 0..7
        int sg = sp ^ (r & 7);           // global segment stored in this slot
        gA[it] = A + (m0 + r) * KX + sg * 8;
        gB[it] = B + (n0 + r) * KX + sg * 8;
        lA[it] = As + f * 8;             // 16 B per slot (contiguous in lane)
        lB[it] = Bs + f * 8;
    }
    const ushortT* pA[2];
    const ushortT* pB[2];
#pragma unroll
    for (int t = 0; t < 2; ++t) {
        pA[t] = As + (wm + t * 32 + l32) * 64;
        pB[t] = Bs + (wn + t * 32 + l32) * 64;
    }

    for (int k0 = 0; k0 < KX; k0 += 64) {
#pragma unroll
        for (int it = 0; it < 4; ++it) {
            __builtin_amdgcn_global_load_lds(
                (const __attribute__((address_space(1))) unsigned*)(const void*)(gA[it] + k0),
                (__attribute__((address_space(3))) unsigned*)(void*)lA[it], 16, 0, 0);
            __builtin_amdgcn_global_load_lds(
                (const __attribute__((address_space(1))) unsigned*)(const void*)(gB[it] + k0),
                (__attribute__((address_space(3))) unsigned*)(void*)lB[it], 16, 0, 0);
        }
        __syncthreads();
#pragma unroll
        for (int kb = 0; kb < 4; ++kb) {
            const int so = ((kb * 2 + h) ^ rx7) * 8;   // swizzled seg offset
            short8 a0 = *(const short8*)(pA[0] + so);
            short8 a1 = *(const short8*)(pA[1] + so);
            short8 b0 = *(const short8*)(pB[0] + so);
            short8 b1 = *(const short8*)(pB[1] + so);
            acc[0][0] = __builtin_amdgcn_mfma_f32_32x32x16_bf16(a0, b0, acc[0][0], 0, 0, 0);
            acc[0][1] = __builtin_amdgcn_mfma_f32_32x32x16_bf16(a0, b1, acc[0][1], 0, 0, 0);
            acc[1][0] = __builtin_amdgcn_mfma_f32_32x32x16_bf16(a1, b0, acc[1][0], 0, 0, 0);
            acc[1][1] = __builtin_amdgcn_mfma_f32_32x32x16_bf16(a1, b1, acc[1][1], 0, 0, 0);
        }
        __syncthreads();
    }
    // C/D: col=lane&31, row=(reg&3)+8*(reg>>2)+4*h  [m74/m101 verified]
#pragma unroll
    for (int ti = 0; ti < 2; ++ti)
#pragma unroll
        for (int tj = 0; tj < 2; ++tj) {
            long long col = n0 + wn + tj * 32 + l32;
            long long rb  = m0 + wm + ti * 32 + 4 * h;
#pragma unroll
            for (int reg = 0; reg < 16; ++reg) {
                long long row = rb + (reg & 3) + 8 * (reg >> 2);
                C[row * ldc + col] = acc[ti][tj][reg];
            }
        }
}

// ---------------------------------------------------------------------------
// Gate kernel: one block/row, keys in registers, exact tie-correct top-k via
// bitwise binary search (early exit when count==k). scores may equal outA
// (in-place: each thread writes only indices it itself read).
// ---------------------------------------------------------------------------
__device__ __forceinline__ unsigned floatToKey(float f) {
    unsigned b = __float_as_uint(f);
    return (b & 0x80000000u) ? ~b : (b | 0x80000000u);
}
__device__ __forceinline__ float keyToFloat(unsigned key) {
    unsigned b = (key & 0x80000000u) ? (key & 0x7FFFFFFFu) : ~key;
    return __uint_as_float(b);
}
__device__ __forceinline__ float egate(float raw) {
    float g = raw > 0.f ? raw : 1e-8f * __expf(raw);
    return expf(g) - 1.f;
}

template <int NV, bool VLOAD, bool VSTORE>
__global__ __launch_bounds__(256) void gate_kernel2(
    const float* __restrict__ scores, int N,
    const float* __restrict__ tau4, int tauA, int tauB,
    int ksel, float* __restrict__ outA, float* __restrict__ outB,
    float* __restrict__ colA, float* __restrict__ colB)
{
    __shared__ int s_i[4];
    __shared__ unsigned s_u[4];
    __shared__ float s_f[8];
    const int tid = threadIdx.x, lane = tid & 63, wv = tid >> 6;
    const int row = blockIdx.x;
    const bool hasB = (outB != nullptr);
    const float* srow = scores + (size_t)row * N;

    unsigned keys[NV * 4];
    unsigned kmax = 0u;
#pragma unroll
    for (int i = 0; i < NV; i++) {
        float v0, v1, v2, v3;
        const size_t nb = (size_t)(i * 256 + tid) * 4;
        if (VLOAD) {
            float4 v = *(const float4*)(srow + nb);
            v0 = v.x; v1 = v.y; v2 = v.z; v3 = v.w;
        } else {
            v0 = srow[nb + 0]; v1 = srow[nb + 1];
            v2 = srow[nb + 2]; v3 = srow[nb + 3];
        }
        unsigned a = floatToKey(v0), b = floatToKey(v1);
        unsigned c = floatToKey(v2), d = floatToKey(v3);
        keys[i * 4 + 0] = a; keys[i * 4 + 1] = b;
        keys[i * 4 + 2] = c; keys[i * 4 + 3] = d;
        unsigned m1 = a > b ? a : b, m2 = c > d ? c : d;
        m1 = m1 > m2 ? m1 : m2;
        kmax = kmax > m1 ? kmax : m1;
    }
#pragma unroll
    for (int o = 32; o > 0; o >>= 1) {
        unsigned x = __shfl_down(kmax, o, 64);
        kmax = kmax > x ? kmax : x;
    }
    if (lane == 0) s_u[wv] = kmax;
    __syncthreads();
    { unsigned a = s_u[0], b = s_u[1], c = s_u[2], d = s_u[3];
      unsigned m1 = a > b ? a : b, m2 = c > d ? c : d; kmax = m1 > m2 ? m1 : m2; }
    __syncthreads();

    unsigned lo = 0u, hi = kmax, vk;
    for (;;) {
        if (lo >= hi) { vk = lo; break; }
        unsigned mid = lo + ((hi - lo + 1u) >> 1);
        int c = 0;
#pragma unroll
        for (int i = 0; i < NV * 4; i++) c += (keys[i] >= mid) ? 1 : 0;
#pragma unroll
        for (int o = 32; o > 0; o >>= 1) c += __shfl_down(c, o, 64);
        if (lane == 0) s_i[wv] = c;
        __syncthreads();
        int total = s_i[0] + s_i[1] + s_i[2] + s_i[3];
        __syncthreads();
        if (total == ksel) { vk = mid; break; }   // exact top-k set isolated
        if (total > ksel) lo = mid; else hi = mid - 1u;
    }

    const float tA = tau4[(size_t)row * 4 + tauA];
    const float tB = hasB ? tau4[(size_t)row * 4 + tauB] : 0.f;
    float sA = 0.f, sB = 0.f;
#pragma unroll
    for (int i = 0; i < NV * 4; i++) {
        if (keys[i] >= vk) {
            float s = keyToFloat(keys[i]);
            sA += egate(s - tA);
            if (hasB) sB += egate(s - tB);
        }
    }
#pragma unroll
    for (int o = 32; o > 0; o >>= 1) {
        sA += __shfl_down(sA, o, 64);
        sB += __shfl_down(sB, o, 64);
    }
    if (lane == 0) { s_f[wv] = sA; s_f[4 + wv] = sB; }
    __syncthreads();
    sA = s_f[0] + s_f[1] + s_f[2] + s_f[3];
    sB = s_f[4] + s_f[5] + s_f[6] + s_f[7];

    const float smax = keyToFloat(kmax);
    const float scaleA = tanhf(egate(smax - tA)) / (sA + 1e-8f);
    const float scaleB = hasB ? tanhf(egate(smax - tB)) / (sB + 1e-8f) : 0.f;

    float* orowA = outA + (size_t)row * N;
    float* orowB = hasB ? outB + (size_t)row * N : nullptr;
#pragma unroll
    for (int i = 0; i < NV; i++) {
        const size_t nb = (size_t)(i * 256 + tid) * 4;
        float ga[4], gb[4];
#pragma unroll
        for (int j = 0; j < 4; j++) {
            unsigned key = keys[i * 4 + j];
            float vA = 0.f, vB = 0.f;
            if (key >= vk) {
                float s = keyToFloat(key);
                vA = egate(s - tA) * scaleA;
                atomicAdd(&colA[nb + j], vA);
                if (hasB) { vB = egate(s - tB) * scaleB; atomicAdd(&colB[nb + j], vB); }
            }
            ga[j] = vA; gb[j] = vB;
        }
        if (VSTORE) {
            *(float4*)(orowA + nb) = make_float4(ga[0], ga[1], ga[2], ga[3]);
            if (hasB) *(float4*)(orowB + nb) = make_float4(gb[0], gb[1], gb[2], gb[3]);
        } else {
#pragma unroll
            for (int j = 0; j < 4; j++) {
                orowA[nb + j] = ga[j];
                if (hasB) orowB[nb + j] = gb[j];
            }
        }
    }
}

// ---------------------------------------------------------------------------
// Aux kernel
// ---------------------------------------------------------------------------
__global__ __launch_bounds__(256) void aux_kernel(
    const float* __restrict__ colsum,
    float* __restrict__ auxAttn, float* __restrict__ auxKnow)
{
    __shared__ float s_a[4];
    __shared__ float s_b[4];
    const int tid = threadIdx.x;
    const int lane = tid & 63, wv = tid >> 6;
    const float invM = 1.f / 4096.f;

    float sa = 0.f;
    const float tqk = 1.f / 4096.f;
    for (int i = tid; i < 3 * N_QK; i += 256) {
        float m = colsum[i] * invM - tqk;
        sa += m * m;
    }
    float sk = 0.f;
    const float tkn = 1.f / 8192.f;
    for (int i = tid; i < N_KNOW; i += 256) {
        float m = colsum[3 * N_QK + i] * invM - tkn;
        sk += m * m;
    }
#pragma unroll
    for (int o = 32; o > 0; o >>= 1) {
        sa += __shfl_down(sa, o, 64);
        sk += __shfl_down(sk, o, 64);
    }
    if (lane == 0) { s_a[wv] = sa; s_b[wv] = sk; }
    __syncthreads();
    if (tid == 0) {
        auxAttn[0] = (s_a[0] + s_a[1] + s_a[2] + s_a[3]) * 4096.f;
        auxKnow[0] = (s_b[0] + s_b[1] + s_b[2] + s_b[3]) * 8192.f;
    }
}

// ---------------------------------------------------------------------------
// Launch
// ---------------------------------------------------------------------------
extern "C" void kernel_launch(void* const* d_in, const int* in_sizes, int n_in,
                              void* d_out, int out_size, void* d_ws, size_t ws_size,
                              hipStream_t stream)
{
    const float* x        = (const float*)d_in[0];
    const float* qk_emb   = (const float*)d_in[1];
    const float* v_emb    = (const float*)d_in[2];
    const float* know_emb = (const float*)d_in[3];
    const float* w_attn   = (const float*)d_in[4];
    const float* b_attn   = (const float*)d_in[5];
    const float* w_know   = (const float*)d_in[6];
    const float* b_know   = (const float*)d_in[7];
    float* out = (float*)d_out;

    const long long M = M_ROWS;
    const long long rowB = (long long)KX * 2;  // 8192 B per bf16x4 row

    float* gQ   = out;
    float* gK   = gQ + (size_t)M * N_QK;
    float* gV   = gK + (size_t)M * N_QK;
    float* auxA = gV + (size_t)M * N_QK;
    float* gKn  = auxA + 1;                    // NOTE: only 4-byte aligned
    float* auxK = gKn + (size_t)M * N_KNOW;

    // know scores scratch = [gQ|gK] (128 MB, 16B-aligned, free before qk stage)
    float* knowScratch = gQ;

    // ---- ws plan (long long arithmetic; scores live in d_out) ----
    const long long nColsum = 3 * N_QK + N_KNOW;
    const long long tail_bytes = (M * 4 + nColsum) * 4;
    long long tailStart = ((long long)ws_size - tail_bytes) & ~255LL;
    float* tau4 = (float*)((char*)d_ws + tailStart);
    float* colsums = tau4 + (size_t)M * 4;

    long long ra, nb;
    if (M * rowB + 128 * rowB <= tailStart) {
        ra = M;
        nb = ((tailStart - M * rowB) / rowB / 128) * 128;
    } else {
        ra = ((tailStart / 2) / rowB / 128) * 128;
        if (ra < 128) ra = 128;
        if (ra > M) ra = M;
        nb = ((tailStart - ra * rowB) / rowB / 128) * 128;
        if (nb < 128) nb = 128;
    }
    ushortT* A_ext = (ushortT*)d_ws;
    ushortT* B_ext = (ushortT*)((char*)d_ws + ra * rowB);

    hipMemsetAsync(colsums, 0, nColsum * sizeof(float), stream);
    tau_kernel<<<(int)M, 256, 0, stream>>>(x, w_attn, b_attn, w_know, b_know, tau4, DIM);

    bool aConv = false;
    auto runGemm = [&](const float* emb, int N, float* scoreBuf) {
        long long NB = nb < N ? nb : N;
        for (long long n0 = 0; n0 < N; n0 += NB) {
            long long nc = (N - n0 < NB) ? (N - n0) : NB;
            {
                int nel4 = (int)(nc * 256);
                convert_ext<false><<<(nel4 + 255) / 256, 256, 0, stream>>>(
                    emb + n0 * DIM, B_ext, nel4);
            }
            for (long long a0 = 0; a0 < M; a0 += ra) {
                long long ac = (M - a0 < ra) ? (M - a0) : ra;
                if (ra < M || !aConv) {
                    int nel4 = (int)(ac * 256);
                    convert_ext<true><<<(nel4 + 255) / 256, 256, 0, stream>>>(
                        x + a0 * DIM, A_ext, nel4);
                    if (ra >= M) aConv = true;
                }
                gemm_bt_bf16x4<<<dim3((unsigned)(nc / 128), (unsigned)(ac / 128)), 256, 0, stream>>>(
                    A_ext, B_ext, scoreBuf + a0 * N + n0, N);
            }
        }
    };

    // ---- 1) KNOW first: scores -> [gQ|gK] scratch; gate -> gKn ----
    runGemm(know_emb, N_KNOW, knowScratch);
    gate_kernel2<8, true, false><<<(int)M, 256, 0, stream>>>(
        knowScratch, N_KNOW, tau4, 3, -1, 128, gKn, nullptr,
        colsums + 3 * N_QK, nullptr);

    // ---- 2) QK: scores -> gQ (in-place gate -> gQ + gK, shared selection) ----
    runGemm(qk_emb, N_QK, gQ);
    gate_kernel2<4, true, true><<<(int)M, 256, 0, stream>>>(
        gQ, N_QK, tau4, 0, 1, 64, gQ, gK, colsums, colsums + N_QK);

    // ---- 3) V: scores -> gV (in-place) ----
    runGemm(v_emb, N_QK, gV);
    gate_kernel2<4, true, true><<<(int)M, 256, 0, stream>>>(
        gV, N_QK, tau4, 2, -1, 64, gV, nullptr, colsums + 2 * N_QK, nullptr);

    aux_kernel<<<1, 256, 0, stream>>>(colsums, auxA, auxK);
}

// Round 7
// 1096.907 us; speedup vs baseline: 1.1029x; 1.1029x over previous
//
#include <hip/hip_runtime.h>
#include <hip/hip_bf16.h>

// ---------------------------------------------------------------------------
// B=2,S=2048,D=1024; M=4096 rows. N_QK=N_V=4096, N_KNOW=8192.
// ONE fused GEMM over N=16384 (qk|v|know) reading fp32 inputs directly:
// staging splits each fp32 into bf16 hi/lo in-register (bit-identical to the
// old convert_ext) and stages four LDS tiles AH/AL/BH/BL (128x32 each).
// Per K-block: acc += Ah.Bh + Ah.Bl + Al.Bh + Al.Bl  (exact product of the
// 2-term splits) -> fp32-class scores. 32x32x16 MFMA, 32 MFMA per barrier.
// Scores land in d_out regions; gates run in-place (exact tie-correct top-k
// via bitwise binary search). ws holds only tau4 + colsums (147 KB).
// ---------------------------------------------------------------------------

#define M_ROWS 4096
#define DIM    1024
#define N_QK   4096
#define N_KNOW 8192

typedef unsigned short ushortT;
typedef __attribute__((ext_vector_type(8)))  short short8;   // 8 bf16 (4 VGPR)
typedef __attribute__((ext_vector_type(16))) float f32x16;

// ---------------------------------------------------------------------------
// tau kernel
// ---------------------------------------------------------------------------
__global__ __launch_bounds__(256) void tau_kernel(
    const float* __restrict__ x, const float* __restrict__ w_attn,
    const float* __restrict__ b_attn, const float* __restrict__ w_know,
    const float* __restrict__ b_know, float* __restrict__ tau4, int D)
{
    __shared__ float s_f[4][4];
    const int row = blockIdx.x;
    const int tid = threadIdx.x;
    const float* xr = x + (size_t)row * D;
    float p0 = 0.f, p1 = 0.f, p2 = 0.f, p3 = 0.f;
    for (int d = tid; d < D; d += 256) {
        float xv = xr[d];
        p0 += xv * w_attn[d * 3 + 0];
        p1 += xv * w_attn[d * 3 + 1];
        p2 += xv * w_attn[d * 3 + 2];
        p3 += xv * w_know[d];
    }
#pragma unroll
    for (int o = 32; o > 0; o >>= 1) {
        p0 += __shfl_down(p0, o, 64);
        p1 += __shfl_down(p1, o, 64);
        p2 += __shfl_down(p2, o, 64);
        p3 += __shfl_down(p3, o, 64);
    }
    const int lane = tid & 63, wv = tid >> 6;
    if (lane == 0) { s_f[wv][0] = p0; s_f[wv][1] = p1; s_f[wv][2] = p2; s_f[wv][3] = p3; }
    __syncthreads();
    if (tid < 4) {
        float v = s_f[0][tid] + s_f[1][tid] + s_f[2][tid] + s_f[3][tid];
        v += (tid < 3) ? b_attn[tid] : b_know[0];
        tau4[(size_t)row * 4 + tid] = v;
    }
}

// ---------------------------------------------------------------------------
// split4: one float4 -> 4 bf16 hi (8B) + 4 bf16 lo (8B). Same element math
// as rounds 4-6 (__float2bfloat16 RNE; residual exact in fp32).
// ---------------------------------------------------------------------------
__device__ __forceinline__ void split4(const float4 v, uint2& H, uint2& L) {
    float vv[4] = {v.x, v.y, v.z, v.w};
    unsigned h[4], l[4];
#pragma unroll
    for (int i = 0; i < 4; i++) {
        __hip_bfloat16 hb = __float2bfloat16(vv[i]);
        float r = vv[i] - __bfloat162float(hb);
        __hip_bfloat16 lb = __float2bfloat16(r);
        h[i] = *(ushortT*)&hb;
        l[i] = *(ushortT*)&lb;
    }
    H.x = h[0] | (h[1] << 16); H.y = h[2] | (h[3] << 16);
    L.x = l[0] | (l[1] << 16); L.y = l[2] | (l[3] << 16);
}

// ---------------------------------------------------------------------------
// Fused GEMM: C[m][n] = x[m][:] . emb[n][:]  (fp32 in, fp32 out) via bf16x4.
// Grid (128, 32): blockIdx.x selects region: [0,32)=qk, [32,64)=v, [64,128)=know.
// 128x128 tile, K_phys=32/barrier. LDS: AH/AL/BH/BL 128x32 bf16 (8 KB each).
// Tile row = 64 B = 4 segs x 16 B; slot (r, sp) holds seg sp^(r&3).
//  - frag ds_read_b128: 64 lanes cover all 8 bank-groups 8-deep = 8 cyc floor
//  - staging ds_write_b64: 4-deep = 4 cyc floor
// Next K-block prefetched into VGPRs after the first barrier (loads stay in
// flight across s_barrier; no vmcnt(0) drain like global_load_lds).
// ---------------------------------------------------------------------------
__global__ __launch_bounds__(256) void gemm_fused(
    const float* __restrict__ x, const float* __restrict__ qk_emb,
    const float* __restrict__ v_emb, const float* __restrict__ know_emb,
    float* __restrict__ gQ, float* __restrict__ gV, float* __restrict__ gKn)
{
    __shared__ ushortT AH[128 * 32];
    __shared__ ushortT AL[128 * 32];
    __shared__ ushortT BH[128 * 32];
    __shared__ ushortT BL[128 * 32];
    const int tid = threadIdx.x;
    const int wave = tid >> 6, lane = tid & 63;
    const int l32 = lane & 31, h = lane >> 5;
    const int rx3 = l32 & 3;
    const int wm = (wave >> 1) * 64, wn = (wave & 1) * 64;
    const long long m0 = (long long)blockIdx.y * 128;
    const int nblk = blockIdx.x;

    const float* Bsrc; float* C; long long ldc; long long n0;
    if (nblk < 32)      { Bsrc = qk_emb;   C = gQ;  ldc = N_QK;   n0 = (long long)nblk * 128; }
    else if (nblk < 64) { Bsrc = v_emb;    C = gV;  ldc = N_QK;   n0 = (long long)(nblk - 32) * 128; }
    else                { Bsrc = know_emb; C = gKn; ldc = N_KNOW; n0 = (long long)(nblk - 64) * 128; }

    // staging plan: 4 float4 per thread per matrix per K-block
    const float* gAp[4]; const float* gBp[4]; int offS[4];
#pragma unroll
    for (int it = 0; it < 4; ++it) {
        int f = it * 256 + tid;       // 0..1023
        int r = f >> 3, c4 = f & 7;   // row 0..127, float4 idx (k = c4*4)
        offS[it] = r * 64 + (((c4 >> 1) ^ (r & 3)) << 4) + ((c4 & 1) << 3);
        gAp[it] = x    + (m0 + r) * DIM + c4 * 4;
        gBp[it] = Bsrc + (n0 + r) * DIM + c4 * 4;
    }
    const char* aHp[2]; const char* aLp[2]; const char* bHp[2]; const char* bLp[2];
#pragma unroll
    for (int t = 0; t < 2; ++t) {
        int ra = wm + t * 32 + l32, rb = wn + t * 32 + l32;
        aHp[t] = (const char*)AH + ra * 64;
        aLp[t] = (const char*)AL + ra * 64;
        bHp[t] = (const char*)BH + rb * 64;
        bLp[t] = (const char*)BL + rb * 64;
    }

    f32x16 acc[2][2] = {};
    float4 bufA[4], bufB[4];
#pragma unroll
    for (int it = 0; it < 4; ++it) {
        bufA[it] = *(const float4*)(gAp[it]);
        bufB[it] = *(const float4*)(gBp[it]);
    }

    for (int k0 = 0; k0 < DIM; k0 += 32) {
#pragma unroll
        for (int it = 0; it < 4; ++it) {
            uint2 Hh, Ll;
            split4(bufA[it], Hh, Ll);
            *(uint2*)((char*)AH + offS[it]) = Hh;
            *(uint2*)((char*)AL + offS[it]) = Ll;
            split4(bufB[it], Hh, Ll);
            *(uint2*)((char*)BH + offS[it]) = Hh;
            *(uint2*)((char*)BL + offS[it]) = Ll;
        }
        __syncthreads();
        if (k0 + 32 < DIM) {
#pragma unroll
            for (int it = 0; it < 4; ++it) {
                bufA[it] = *(const float4*)(gAp[it] + k0 + 32);
                bufB[it] = *(const float4*)(gBp[it] + k0 + 32);
            }
        }
#pragma unroll
        for (int kb = 0; kb < 2; ++kb) {
            const int so = ((kb * 2 + h) ^ rx3) * 16;   // swizzled seg byte off
            short8 aH[2], aL[2], bH[2], bL[2];
#pragma unroll
            for (int t = 0; t < 2; ++t) {
                aH[t] = *(const short8*)(aHp[t] + so);
                aL[t] = *(const short8*)(aLp[t] + so);
                bH[t] = *(const short8*)(bHp[t] + so);
                bL[t] = *(const short8*)(bLp[t] + so);
            }
#pragma unroll
            for (int i = 0; i < 2; ++i)
#pragma unroll
                for (int j = 0; j < 2; ++j) {
                    acc[i][j] = __builtin_amdgcn_mfma_f32_32x32x16_bf16(aH[i], bH[j], acc[i][j], 0, 0, 0);
                    acc[i][j] = __builtin_amdgcn_mfma_f32_32x32x16_bf16(aH[i], bL[j], acc[i][j], 0, 0, 0);
                    acc[i][j] = __builtin_amdgcn_mfma_f32_32x32x16_bf16(aL[i], bH[j], acc[i][j], 0, 0, 0);
                    acc[i][j] = __builtin_amdgcn_mfma_f32_32x32x16_bf16(aL[i], bL[j], acc[i][j], 0, 0, 0);
                }
        }
        __syncthreads();
    }
    // C/D: col=lane&31, row=(reg&3)+8*(reg>>2)+4*h  [m74/m101 verified]
#pragma unroll
    for (int ti = 0; ti < 2; ++ti)
#pragma unroll
        for (int tj = 0; tj < 2; ++tj) {
            long long col = n0 + wn + tj * 32 + l32;
            long long rb  = m0 + wm + ti * 32 + 4 * h;
#pragma unroll
            for (int reg = 0; reg < 16; ++reg) {
                long long row = rb + (reg & 3) + 8 * (reg >> 2);
                C[row * ldc + col] = acc[ti][tj][reg];
            }
        }
}

// ---------------------------------------------------------------------------
// Gate kernel: one block/row, keys in registers, exact tie-correct top-k via
// bitwise binary search (early exit when count==k). scores may equal outA
// (in-place: each thread writes only indices it itself read).
// ---------------------------------------------------------------------------
__device__ __forceinline__ unsigned floatToKey(float f) {
    unsigned b = __float_as_uint(f);
    return (b & 0x80000000u) ? ~b : (b | 0x80000000u);
}
__device__ __forceinline__ float keyToFloat(unsigned key) {
    unsigned b = (key & 0x80000000u) ? (key & 0x7FFFFFFFu) : ~key;
    return __uint_as_float(b);
}
__device__ __forceinline__ float egate(float raw) {
    float g = raw > 0.f ? raw : 1e-8f * __expf(raw);
    return expf(g) - 1.f;
}

template <int NV, bool VLOAD, bool VSTORE>
__global__ __launch_bounds__(256) void gate_kernel2(
    const float* __restrict__ scores, int N,
    const float* __restrict__ tau4, int tauA, int tauB,
    int ksel, float* __restrict__ outA, float* __restrict__ outB,
    float* __restrict__ colA, float* __restrict__ colB)
{
    __shared__ int s_i[4];
    __shared__ unsigned s_u[4];
    __shared__ float s_f[8];
    const int tid = threadIdx.x, lane = tid & 63, wv = tid >> 6;
    const int row = blockIdx.x;
    const bool hasB = (outB != nullptr);
    const float* srow = scores + (size_t)row * N;

    unsigned keys[NV * 4];
    unsigned kmax = 0u;
#pragma unroll
    for (int i = 0; i < NV; i++) {
        float v0, v1, v2, v3;
        const size_t nb = (size_t)(i * 256 + tid) * 4;
        if (VLOAD) {
            float4 v = *(const float4*)(srow + nb);
            v0 = v.x; v1 = v.y; v2 = v.z; v3 = v.w;
        } else {
            v0 = srow[nb + 0]; v1 = srow[nb + 1];
            v2 = srow[nb + 2]; v3 = srow[nb + 3];
        }
        unsigned a = floatToKey(v0), b = floatToKey(v1);
        unsigned c = floatToKey(v2), d = floatToKey(v3);
        keys[i * 4 + 0] = a; keys[i * 4 + 1] = b;
        keys[i * 4 + 2] = c; keys[i * 4 + 3] = d;
        unsigned m1 = a > b ? a : b, m2 = c > d ? c : d;
        m1 = m1 > m2 ? m1 : m2;
        kmax = kmax > m1 ? kmax : m1;
    }
#pragma unroll
    for (int o = 32; o > 0; o >>= 1) {
        unsigned x = __shfl_down(kmax, o, 64);
        kmax = kmax > x ? kmax : x;
    }
    if (lane == 0) s_u[wv] = kmax;
    __syncthreads();
    { unsigned a = s_u[0], b = s_u[1], c = s_u[2], d = s_u[3];
      unsigned m1 = a > b ? a : b, m2 = c > d ? c : d; kmax = m1 > m2 ? m1 : m2; }
    __syncthreads();

    unsigned lo = 0u, hi = kmax, vk;
    for (;;) {
        if (lo >= hi) { vk = lo; break; }
        unsigned mid = lo + ((hi - lo + 1u) >> 1);
        int c = 0;
#pragma unroll
        for (int i = 0; i < NV * 4; i++) c += (keys[i] >= mid) ? 1 : 0;
#pragma unroll
        for (int o = 32; o > 0; o >>= 1) c += __shfl_down(c, o, 64);
        if (lane == 0) s_i[wv] = c;
        __syncthreads();
        int total = s_i[0] + s_i[1] + s_i[2] + s_i[3];
        __syncthreads();
        if (total == ksel) { vk = mid; break; }   // exact top-k set isolated
        if (total > ksel) lo = mid; else hi = mid - 1u;
    }

    const float tA = tau4[(size_t)row * 4 + tauA];
    const float tB = hasB ? tau4[(size_t)row * 4 + tauB] : 0.f;
    float sA = 0.f, sB = 0.f;
#pragma unroll
    for (int i = 0; i < NV * 4; i++) {
        if (keys[i] >= vk) {
            float s = keyToFloat(keys[i]);
            sA += egate(s - tA);
            if (hasB) sB += egate(s - tB);
        }
    }
#pragma unroll
    for (int o = 32; o > 0; o >>= 1) {
        sA += __shfl_down(sA, o, 64);
        sB += __shfl_down(sB, o, 64);
    }
    if (lane == 0) { s_f[wv] = sA; s_f[4 + wv] = sB; }
    __syncthreads();
    sA = s_f[0] + s_f[1] + s_f[2] + s_f[3];
    sB = s_f[4] + s_f[5] + s_f[6] + s_f[7];

    const float smax = keyToFloat(kmax);
    const float scaleA = tanhf(egate(smax - tA)) / (sA + 1e-8f);
    const float scaleB = hasB ? tanhf(egate(smax - tB)) / (sB + 1e-8f) : 0.f;

    float* orowA = outA + (size_t)row * N;
    float* orowB = hasB ? outB + (size_t)row * N : nullptr;
#pragma unroll
    for (int i = 0; i < NV; i++) {
        const size_t nb = (size_t)(i * 256 + tid) * 4;
        float ga[4], gb[4];
#pragma unroll
        for (int j = 0; j < 4; j++) {
            unsigned key = keys[i * 4 + j];
            float vA = 0.f, vB = 0.f;
            if (key >= vk) {
                float s = keyToFloat(key);
                vA = egate(s - tA) * scaleA;
                atomicAdd(&colA[nb + j], vA);
                if (hasB) { vB = egate(s - tB) * scaleB; atomicAdd(&colB[nb + j], vB); }
            }
            ga[j] = vA; gb[j] = vB;
        }
        if (VSTORE) {
            *(float4*)(orowA + nb) = make_float4(ga[0], ga[1], ga[2], ga[3]);
            if (hasB) *(float4*)(orowB + nb) = make_float4(gb[0], gb[1], gb[2], gb[3]);
        } else {
#pragma unroll
            for (int j = 0; j < 4; j++) {
                orowA[nb + j] = ga[j];
                if (hasB) orowB[nb + j] = gb[j];
            }
        }
    }
}

// ---------------------------------------------------------------------------
// Aux kernel
// ---------------------------------------------------------------------------
__global__ __launch_bounds__(256) void aux_kernel(
    const float* __restrict__ colsum,
    float* __restrict__ auxAttn, float* __restrict__ auxKnow)
{
    __shared__ float s_a[4];
    __shared__ float s_b[4];
    const int tid = threadIdx.x;
    const int lane = tid & 63, wv = tid >> 6;
    const float invM = 1.f / 4096.f;

    float sa = 0.f;
    const float tqk = 1.f / 4096.f;
    for (int i = tid; i < 3 * N_QK; i += 256) {
        float m = colsum[i] * invM - tqk;
        sa += m * m;
    }
    float sk = 0.f;
    const float tkn = 1.f / 8192.f;
    for (int i = tid; i < N_KNOW; i += 256) {
        float m = colsum[3 * N_QK + i] * invM - tkn;
        sk += m * m;
    }
#pragma unroll
    for (int o = 32; o > 0; o >>= 1) {
        sa += __shfl_down(sa, o, 64);
        sk += __shfl_down(sk, o, 64);
    }
    if (lane == 0) { s_a[wv] = sa; s_b[wv] = sk; }
    __syncthreads();
    if (tid == 0) {
        auxAttn[0] = (s_a[0] + s_a[1] + s_a[2] + s_a[3]) * 4096.f;
        auxKnow[0] = (s_b[0] + s_b[1] + s_b[2] + s_b[3]) * 8192.f;
    }
}

// ---------------------------------------------------------------------------
// Launch: 7 dispatches total.
// ---------------------------------------------------------------------------
extern "C" void kernel_launch(void* const* d_in, const int* in_sizes, int n_in,
                              void* d_out, int out_size, void* d_ws, size_t ws_size,
                              hipStream_t stream)
{
    const float* x        = (const float*)d_in[0];
    const float* qk_emb   = (const float*)d_in[1];
    const float* v_emb    = (const float*)d_in[2];
    const float* know_emb = (const float*)d_in[3];
    const float* w_attn   = (const float*)d_in[4];
    const float* b_attn   = (const float*)d_in[5];
    const float* w_know   = (const float*)d_in[6];
    const float* b_know   = (const float*)d_in[7];
    float* out = (float*)d_out;

    const long long M = M_ROWS;

    float* gQ   = out;
    float* gK   = gQ + (size_t)M * N_QK;
    float* gV   = gK + (size_t)M * N_QK;
    float* auxA = gV + (size_t)M * N_QK;
    float* gKn  = auxA + 1;                    // only 4-byte aligned: scalar path
    float* auxK = gKn + (size_t)M * N_KNOW;

    // ws: tau4 (64 KB) + colsums (80 KB) only
    float* tau4 = (float*)d_ws;
    float* colsums = tau4 + (size_t)M * 4;
    const long long nColsum = 3 * N_QK + N_KNOW;

    hipMemsetAsync(colsums, 0, nColsum * sizeof(float), stream);
    tau_kernel<<<(int)M, 256, 0, stream>>>(x, w_attn, b_attn, w_know, b_know, tau4, DIM);

    // one merged GEMM: qk|v|know -> gQ / gV / gKn
    gemm_fused<<<dim3(128, 32), 256, 0, stream>>>(
        x, qk_emb, v_emb, know_emb, gQ, gV, gKn);

    // gates (in-place; Q/K share one selection since tau is per-row constant)
    gate_kernel2<4, true, true><<<(int)M, 256, 0, stream>>>(
        gQ, N_QK, tau4, 0, 1, 64, gQ, gK, colsums, colsums + N_QK);
    gate_kernel2<4, true, true><<<(int)M, 256, 0, stream>>>(
        gV, N_QK, tau4, 2, -1, 64, gV, nullptr, colsums + 2 * N_QK, nullptr);
    gate_kernel2<8, false, false><<<(int)M, 256, 0, stream>>>(
        gKn, N_KNOW, tau4, 3, -1, 128, gKn, nullptr, colsums + 3 * N_QK, nullptr);

    aux_kernel<<<1, 256, 0, stream>>>(colsums, auxA, auxK);
}

// Round 8
// 1067.077 us; speedup vs baseline: 1.1337x; 1.0280x over previous
//
#include <hip/hip_runtime.h>
#include <hip/hip_bf16.h>

// ---------------------------------------------------------------------------
// B=2,S=2048,D=1024; M=4096 rows. N_QK=N_V=4096, N_KNOW=8192.
// One fused GEMM over N=16384 (qk|v|know), bf16x4 split, 32x32x16 MFMA.
//  - A pre-split once to A_ext: per row, per 32-elem k-chunk: [32 bf16 H | 32 L]
//    staged via global_load_lds (seg-swizzled global addr, flat LDS dst).
//  - B split in-register (split4) and ds_written into the same tile geometry.
//  - LDS tiles AHL/BHL: 128 rows x 128 B (8 segs x 16 B), slot(r,sp) holds
//    global seg sp^(r&7)  [round-6-verified read pattern].
// MFMA accumulation order identical to round 7 -> scores BIT-IDENTICAL.
// Gates: ONE dispatch (know|qk|v), exact tie-correct top-k via bitwise binary
// search (1 barrier/iter, double-buffered counts), coalesced scalar path for
// the 4B-aligned know region. ws: A_ext (chunked) + tau4 + colsums.
// ---------------------------------------------------------------------------

#define M_ROWS 4096
#define DIM    1024
#define N_QK   4096
#define N_KNOW 8192

typedef unsigned short ushortT;
typedef __attribute__((ext_vector_type(8)))  short short8;   // 8 bf16 (4 VGPR)
typedef __attribute__((ext_vector_type(16))) float f32x16;

// ---------------------------------------------------------------------------
// tau kernel
// ---------------------------------------------------------------------------
__global__ __launch_bounds__(256) void tau_kernel(
    const float* __restrict__ x, const float* __restrict__ w_attn,
    const float* __restrict__ b_attn, const float* __restrict__ w_know,
    const float* __restrict__ b_know, float* __restrict__ tau4, int D)
{
    __shared__ float s_f[4][4];
    const int row = blockIdx.x;
    const int tid = threadIdx.x;
    const float* xr = x + (size_t)row * D;
    float p0 = 0.f, p1 = 0.f, p2 = 0.f, p3 = 0.f;
    for (int d = tid; d < D; d += 256) {
        float xv = xr[d];
        p0 += xv * w_attn[d * 3 + 0];
        p1 += xv * w_attn[d * 3 + 1];
        p2 += xv * w_attn[d * 3 + 2];
        p3 += xv * w_know[d];
    }
#pragma unroll
    for (int o = 32; o > 0; o >>= 1) {
        p0 += __shfl_down(p0, o, 64);
        p1 += __shfl_down(p1, o, 64);
        p2 += __shfl_down(p2, o, 64);
        p3 += __shfl_down(p3, o, 64);
    }
    const int lane = tid & 63, wv = tid >> 6;
    if (lane == 0) { s_f[wv][0] = p0; s_f[wv][1] = p1; s_f[wv][2] = p2; s_f[wv][3] = p3; }
    __syncthreads();
    if (tid < 4) {
        float v = s_f[0][tid] + s_f[1][tid] + s_f[2][tid] + s_f[3][tid];
        v += (tid < 3) ? b_attn[tid] : b_know[0];
        tau4[(size_t)row * 4 + tid] = v;
    }
}

// ---------------------------------------------------------------------------
// split4: one float4 -> 4 bf16 hi (8B) + 4 bf16 lo (8B). Bit-identical to
// rounds 4-7 (__float2bfloat16 RNE; residual exact in fp32).
// ---------------------------------------------------------------------------
__device__ __forceinline__ void split4(const float4 v, uint2& H, uint2& L) {
    float vv[4] = {v.x, v.y, v.z, v.w};
    unsigned h[4], l[4];
#pragma unroll
    for (int i = 0; i < 4; i++) {
        __hip_bfloat16 hb = __float2bfloat16(vv[i]);
        float r = vv[i] - __bfloat162float(hb);
        __hip_bfloat16 lb = __float2bfloat16(r);
        h[i] = *(ushortT*)&hb;
        l[i] = *(ushortT*)&lb;
    }
    H.x = h[0] | (h[1] << 16); H.y = h[2] | (h[3] << 16);
    L.x = l[0] | (l[1] << 16); L.y = l[2] | (l[3] << 16);
}

// ---------------------------------------------------------------------------
// convertA: x rows x 1024 fp32 -> A_ext rows x [32 chunks][32 H | 32 L] bf16
// Row stride 2048 ushorts (4 KB). One float4 per thread.
// ---------------------------------------------------------------------------
__global__ __launch_bounds__(256) void convertA(
    const float* __restrict__ src, ushortT* __restrict__ dst, int nElem4)
{
    int g = blockIdx.x * 256 + threadIdx.x;
    if (g >= nElem4) return;
    int row = g >> 8;            // 256 float4 per row
    int c4  = g & 255;           // float4 idx
    int chunk = c4 >> 3, pos = c4 & 7;
    const float4 v = *(const float4*)(src + (size_t)row * DIM + c4 * 4);
    uint2 H, L;
    split4(v, H, L);
    ushortT* base = dst + (size_t)row * 2048 + chunk * 64;
    *(uint2*)(base + pos * 4)      = H;
    *(uint2*)(base + 32 + pos * 4) = L;
}

// ---------------------------------------------------------------------------
// Fused GEMM: C = x . emb^T via bf16x4 (HH+HL+LH+LL), 32x32x16 MFMA.
// Grid (128, rows/128): blockIdx.x: [0,32)=qk, [32,64)=v, [64,128)=know.
// K-chunk = 32. A staged by DMA from A_ext; B split in-register.
// ---------------------------------------------------------------------------
__global__ __launch_bounds__(256) void gemm_fused2(
    const ushortT* __restrict__ Aext, const float* __restrict__ qk_emb,
    const float* __restrict__ v_emb, const float* __restrict__ know_emb,
    float* __restrict__ gQ, float* __restrict__ gV, float* __restrict__ gKn,
    long long rowOff)
{
    __shared__ ushortT AHL[128 * 64];   // 128 rows x 128 B
    __shared__ ushortT BHL[128 * 64];
    const int tid = threadIdx.x;
    const int wave = tid >> 6, lane = tid & 63;
    const int l32 = lane & 31, h = lane >> 5;
    const int rx7 = l32 & 7;
    const int wm = (wave >> 1) * 64, wn = (wave & 1) * 64;
    const long long m0 = (long long)blockIdx.y * 128;
    const int nblk = blockIdx.x;

    const float* Bsrc; float* C; long long ldc; long long n0;
    if (nblk < 32)      { Bsrc = qk_emb;   C = gQ;  ldc = N_QK;   n0 = (long long)nblk * 128; }
    else if (nblk < 64) { Bsrc = v_emb;    C = gV;  ldc = N_QK;   n0 = (long long)(nblk - 32) * 128; }
    else                { Bsrc = know_emb; C = gKn; ldc = N_KNOW; n0 = (long long)(nblk - 64) * 128; }

    // --- staging plans ---
    const ushortT* gAp[4]; ushortT* lAp[4];   // A DMA: flat slot f, swizzled global seg
    const float*   gBp[4]; int offH[4], offL[4];
#pragma unroll
    for (int it = 0; it < 4; ++it) {
        int f = it * 256 + tid;          // 0..1023
        int r = f >> 3, sp = f & 7;
        int sg = sp ^ (r & 7);
        gAp[it] = Aext + (m0 + r) * 2048 + sg * 8;   // + c*64 per chunk
        lAp[it] = AHL + f * 8;                       // 16 B per slot, lane-contig
        int c4 = f & 7;                  // B: float4 idx within chunk
        int s = c4 >> 1, hf = c4 & 1;
        offH[it] = r * 128 + ((s ^ (r & 7)) * 16) + hf * 8;
        offL[it] = r * 128 + (((4 | s) ^ (r & 7)) * 16) + hf * 8;
        gBp[it] = Bsrc + (n0 + r) * DIM + c4 * 4;    // + c*32 per chunk
    }
    const char* pA[2]; const char* pB[2];
#pragma unroll
    for (int t = 0; t < 2; ++t) {
        pA[t] = (const char*)AHL + (wm + t * 32 + l32) * 128;
        pB[t] = (const char*)BHL + (wn + t * 32 + l32) * 128;
    }

    f32x16 acc[2][2] = {};
    float4 bufB[4];
#pragma unroll
    for (int it = 0; it < 4; ++it) bufB[it] = *(const float4*)(gBp[it]);

    for (int c = 0; c < 32; ++c) {
        // stage A (DMA) + B (split + ds_write)
#pragma unroll
        for (int it = 0; it < 4; ++it) {
            __builtin_amdgcn_global_load_lds(
                (const __attribute__((address_space(1))) unsigned*)(const void*)(gAp[it] + c * 64),
                (__attribute__((address_space(3))) unsigned*)(void*)lAp[it], 16, 0, 0);
            uint2 H, L;
            split4(bufB[it], H, L);
            *(uint2*)((char*)BHL + offH[it]) = H;
            *(uint2*)((char*)BHL + offL[it]) = L;
        }
        __syncthreads();
        if (c + 1 < 32) {
#pragma unroll
            for (int it = 0; it < 4; ++it)
                bufB[it] = *(const float4*)(gBp[it] + (c + 1) * 32);
        }
#pragma unroll
        for (int kb = 0; kb < 2; ++kb) {
            const int so = ((kb * 2 + h) ^ rx7) * 16;
            short8 aH[2], aL[2], bH[2], bL[2];
#pragma unroll
            for (int t = 0; t < 2; ++t) {
                aH[t] = *(const short8*)(pA[t] + so);
                aL[t] = *(const short8*)(pA[t] + (so ^ 64));
                bH[t] = *(const short8*)(pB[t] + so);
                bL[t] = *(const short8*)(pB[t] + (so ^ 64));
            }
#pragma unroll
            for (int i = 0; i < 2; ++i)
#pragma unroll
                for (int j = 0; j < 2; ++j) {
                    acc[i][j] = __builtin_amdgcn_mfma_f32_32x32x16_bf16(aH[i], bH[j], acc[i][j], 0, 0, 0);
                    acc[i][j] = __builtin_amdgcn_mfma_f32_32x32x16_bf16(aH[i], bL[j], acc[i][j], 0, 0, 0);
                    acc[i][j] = __builtin_amdgcn_mfma_f32_32x32x16_bf16(aL[i], bH[j], acc[i][j], 0, 0, 0);
                    acc[i][j] = __builtin_amdgcn_mfma_f32_32x32x16_bf16(aL[i], bL[j], acc[i][j], 0, 0, 0);
                }
        }
        __syncthreads();
    }
    // C/D: col=lane&31, row=(reg&3)+8*(reg>>2)+4*h  [m74/m101 verified]
#pragma unroll
    for (int ti = 0; ti < 2; ++ti)
#pragma unroll
        for (int tj = 0; tj < 2; ++tj) {
            long long col = n0 + wn + tj * 32 + l32;
            long long rb  = rowOff + m0 + wm + ti * 32 + 4 * h;
#pragma unroll
            for (int reg = 0; reg < 16; ++reg) {
                long long row = rb + (reg & 3) + 8 * (reg >> 2);
                C[row * ldc + col] = acc[ti][tj][reg];
            }
        }
}

// ---------------------------------------------------------------------------
// Gate body: keys in registers, exact tie-correct top-k via bitwise binary
// search (early exit at count==k; 1 barrier/iter via double-buffered counts).
// In-place safe (each thread writes only indices it read).
// idx(ii): VLOAD -> float4 blocks; else stride-256 coalesced scalars.
// ---------------------------------------------------------------------------
__device__ __forceinline__ unsigned floatToKey(float f) {
    unsigned b = __float_as_uint(f);
    return (b & 0x80000000u) ? ~b : (b | 0x80000000u);
}
__device__ __forceinline__ float keyToFloat(unsigned key) {
    unsigned b = (key & 0x80000000u) ? (key & 0x7FFFFFFFu) : ~key;
    return __uint_as_float(b);
}
__device__ __forceinline__ float egate(float raw) {
    float g = raw > 0.f ? raw : 1e-8f * __expf(raw);
    return expf(g) - 1.f;
}

template <int NV, bool VLOAD, bool VSTORE>
__device__ __forceinline__ void gate_body(
    const float* __restrict__ srow, float tA, float tB, bool hasB, int ksel,
    float* __restrict__ orowA, float* __restrict__ orowB,
    float* __restrict__ colA, float* __restrict__ colB,
    int* s_cnt, unsigned* s_u, float* s_f)
{
    const int tid = threadIdx.x, lane = tid & 63, wv = tid >> 6;

    unsigned keys[NV * 4];
    unsigned kmax = 0u;
#pragma unroll
    for (int i = 0; i < NV; i++) {
        float v0, v1, v2, v3;
        if (VLOAD) {
            float4 v = *(const float4*)(srow + (size_t)(i * 256 + tid) * 4);
            v0 = v.x; v1 = v.y; v2 = v.z; v3 = v.w;
        } else {
            v0 = srow[(i * 4 + 0) * 256 + tid];
            v1 = srow[(i * 4 + 1) * 256 + tid];
            v2 = srow[(i * 4 + 2) * 256 + tid];
            v3 = srow[(i * 4 + 3) * 256 + tid];
        }
        unsigned a = floatToKey(v0), b = floatToKey(v1);
        unsigned c = floatToKey(v2), d = floatToKey(v3);
        keys[i * 4 + 0] = a; keys[i * 4 + 1] = b;
        keys[i * 4 + 2] = c; keys[i * 4 + 3] = d;
        unsigned m1 = a > b ? a : b, m2 = c > d ? c : d;
        m1 = m1 > m2 ? m1 : m2;
        kmax = kmax > m1 ? kmax : m1;
    }
#pragma unroll
    for (int o = 32; o > 0; o >>= 1) {
        unsigned x = __shfl_down(kmax, o, 64);
        kmax = kmax > x ? kmax : x;
    }
    if (lane == 0) s_u[wv] = kmax;
    __syncthreads();
    { unsigned a = s_u[0], b = s_u[1], c = s_u[2], d = s_u[3];
      unsigned m1 = a > b ? a : b, m2 = c > d ? c : d; kmax = m1 > m2 ? m1 : m2; }

    unsigned lo = 0u, hi = kmax, vk;
    int pp = 0;
    for (;;) {
        if (lo >= hi) { vk = lo; break; }
        unsigned mid = lo + ((hi - lo + 1u) >> 1);
        int c = 0;
#pragma unroll
        for (int i = 0; i < NV * 4; i++) c += (keys[i] >= mid) ? 1 : 0;
#pragma unroll
        for (int o = 32; o > 0; o >>= 1) c += __shfl_down(c, o, 64);
        if (lane == 0) s_cnt[pp * 4 + wv] = c;
        __syncthreads();
        int total = s_cnt[pp * 4 + 0] + s_cnt[pp * 4 + 1]
                  + s_cnt[pp * 4 + 2] + s_cnt[pp * 4 + 3];
        pp ^= 1;
        if (total == ksel) { vk = mid; break; }
        if (total > ksel) lo = mid; else hi = mid - 1u;
    }

    float sA = 0.f, sB = 0.f;
#pragma unroll
    for (int i = 0; i < NV * 4; i++) {
        if (keys[i] >= vk) {
            float s = keyToFloat(keys[i]);
            sA += egate(s - tA);
            if (hasB) sB += egate(s - tB);
        }
    }
#pragma unroll
    for (int o = 32; o > 0; o >>= 1) {
        sA += __shfl_down(sA, o, 64);
        sB += __shfl_down(sB, o, 64);
    }
    if (lane == 0) { s_f[wv] = sA; s_f[4 + wv] = sB; }
    __syncthreads();
    sA = s_f[0] + s_f[1] + s_f[2] + s_f[3];
    sB = s_f[4] + s_f[5] + s_f[6] + s_f[7];

    const float smax = keyToFloat(kmax);
    const float scaleA = tanhf(egate(smax - tA)) / (sA + 1e-8f);
    const float scaleB = hasB ? tanhf(egate(smax - tB)) / (sB + 1e-8f) : 0.f;

#pragma unroll
    for (int i = 0; i < NV; i++) {
        float ga[4], gb[4];
        int eidx[4];
#pragma unroll
        for (int j = 0; j < 4; j++) {
            int ii = i * 4 + j;
            int idx = VLOAD ? (i * 1024 + tid * 4 + j) : (ii * 256 + tid);
            eidx[j] = idx;
            unsigned key = keys[ii];
            float vA = 0.f, vB = 0.f;
            if (key >= vk) {
                float s = keyToFloat(key);
                vA = egate(s - tA) * scaleA;
                atomicAdd(&colA[idx], vA);
                if (hasB) { vB = egate(s - tB) * scaleB; atomicAdd(&colB[idx], vB); }
            }
            ga[j] = vA; gb[j] = vB;
        }
        if (VSTORE) {
            *(float4*)(orowA + (size_t)eidx[0]) = make_float4(ga[0], ga[1], ga[2], ga[3]);
            if (hasB) *(float4*)(orowB + (size_t)eidx[0]) = make_float4(gb[0], gb[1], gb[2], gb[3]);
        } else {
#pragma unroll
            for (int j = 0; j < 4; j++) {
                orowA[eidx[j]] = ga[j];
                if (hasB) orowB[eidx[j]] = gb[j];
            }
        }
    }
}

// Merged gate dispatch: [0,4096)=know, [4096,8192)=qk (Q+K), [8192,12288)=v
__global__ __launch_bounds__(256) void gate_all(
    const float* __restrict__ tau4,
    float* __restrict__ gQ, float* __restrict__ gK,
    float* __restrict__ gV, float* __restrict__ gKn,
    float* __restrict__ colsums)
{
    __shared__ int s_cnt[8];
    __shared__ unsigned s_u[4];
    __shared__ float s_f[8];
    const int bid = blockIdx.x;
    if (bid < 4096) {
        const int row = bid;
        const float t = tau4[(size_t)row * 4 + 3];
        gate_body<8, false, false>(
            gKn + (size_t)row * N_KNOW, t, 0.f, false, 128,
            gKn + (size_t)row * N_KNOW, nullptr,
            colsums + 3 * N_QK, nullptr, s_cnt, s_u, s_f);
    } else if (bid < 8192) {
        const int row = bid - 4096;
        const float tA = tau4[(size_t)row * 4 + 0];
        const float tB = tau4[(size_t)row * 4 + 1];
        gate_body<4, true, true>(
            gQ + (size_t)row * N_QK, tA, tB, true, 64,
            gQ + (size_t)row * N_QK, gK + (size_t)row * N_QK,
            colsums, colsums + N_QK, s_cnt, s_u, s_f);
    } else {
        const int row = bid - 8192;
        const float t = tau4[(size_t)row * 4 + 2];
        gate_body<4, true, true>(
            gV + (size_t)row * N_QK, t, 0.f, false, 64,
            gV + (size_t)row * N_QK, nullptr,
            colsums + 2 * N_QK, nullptr, s_cnt, s_u, s_f);
    }
}

// ---------------------------------------------------------------------------
// Aux kernel
// ---------------------------------------------------------------------------
__global__ __launch_bounds__(256) void aux_kernel(
    const float* __restrict__ colsum,
    float* __restrict__ auxAttn, float* __restrict__ auxKnow)
{
    __shared__ float s_a[4];
    __shared__ float s_b[4];
    const int tid = threadIdx.x;
    const int lane = tid & 63, wv = tid >> 6;
    const float invM = 1.f / 4096.f;

    float sa = 0.f;
    const float tqk = 1.f / 4096.f;
    for (int i = tid; i < 3 * N_QK; i += 256) {
        float m = colsum[i] * invM - tqk;
        sa += m * m;
    }
    float sk = 0.f;
    const float tkn = 1.f / 8192.f;
    for (int i = tid; i < N_KNOW; i += 256) {
        float m = colsum[3 * N_QK + i] * invM - tkn;
        sk += m * m;
    }
#pragma unroll
    for (int o = 32; o > 0; o >>= 1) {
        sa += __shfl_down(sa, o, 64);
        sk += __shfl_down(sk, o, 64);
    }
    if (lane == 0) { s_a[wv] = sa; s_b[wv] = sk; }
    __syncthreads();
    if (tid == 0) {
        auxAttn[0] = (s_a[0] + s_a[1] + s_a[2] + s_a[3]) * 4096.f;
        auxKnow[0] = (s_b[0] + s_b[1] + s_b[2] + s_b[3]) * 8192.f;
    }
}

// ---------------------------------------------------------------------------
// Launch
// ---------------------------------------------------------------------------
extern "C" void kernel_launch(void* const* d_in, const int* in_sizes, int n_in,
                              void* d_out, int out_size, void* d_ws, size_t ws_size,
                              hipStream_t stream)
{
    const float* x        = (const float*)d_in[0];
    const float* qk_emb   = (const float*)d_in[1];
    const float* v_emb    = (const float*)d_in[2];
    const float* know_emb = (const float*)d_in[3];
    const float* w_attn   = (const float*)d_in[4];
    const float* b_attn   = (const float*)d_in[5];
    const float* w_know   = (const float*)d_in[6];
    const float* b_know   = (const float*)d_in[7];
    float* out = (float*)d_out;

    const long long M = M_ROWS;

    float* gQ   = out;
    float* gK   = gQ + (size_t)M * N_QK;
    float* gV   = gK + (size_t)M * N_QK;
    float* auxA = gV + (size_t)M * N_QK;
    float* gKn  = auxA + 1;                    // only 4-byte aligned: scalar path
    float* auxK = gKn + (size_t)M * N_KNOW;

    // ---- ws plan: [A_ext chunk][ ... ][tau4|colsums] ----
    const long long nColsum = 3 * N_QK + N_KNOW;
    const long long tail_bytes = (M * 4 + nColsum) * 4;
    long long tailStart = ((long long)ws_size - tail_bytes) & ~255LL;
    float* tau4 = (float*)((char*)d_ws + tailStart);
    float* colsums = tau4 + (size_t)M * 4;

    const long long rowB = 4096;               // A_ext bytes per row
    long long ra = (tailStart / rowB / 128) * 128;
    if (ra > M) ra = M;
    if (ra < 128) ra = 128;
    ushortT* A_ext = (ushortT*)d_ws;

    hipMemsetAsync(colsums, 0, nColsum * sizeof(float), stream);
    tau_kernel<<<(int)M, 256, 0, stream>>>(x, w_attn, b_attn, w_know, b_know, tau4, DIM);

    for (long long a0 = 0; a0 < M; a0 += ra) {
        long long ac = (M - a0 < ra) ? (M - a0) : ra;
        int nel4 = (int)(ac * 256);
        convertA<<<(nel4 + 255) / 256, 256, 0, stream>>>(x + a0 * DIM, A_ext, nel4);
        gemm_fused2<<<dim3(128, (unsigned)(ac / 128)), 256, 0, stream>>>(
            A_ext, qk_emb, v_emb, know_emb, gQ, gV, gKn, a0);
    }

    gate_all<<<12288, 256, 0, stream>>>(tau4, gQ, gK, gV, gKn, colsums);

    aux_kernel<<<1, 256, 0, stream>>>(colsums, auxA, auxK);
}